// Round 1
// baseline (8118.715 us; speedup 1.0000x reference)
//
#include <hip/hip_runtime.h>
#include <cstdint>
#include <cstddef>

#define BATCH 256
#define SEQ   512
#define HID   512
#define VOCAB 128

#define BT        16            // batch rows per block
#define NBLK      (BATCH/BT)    // 16 persistent blocks, one per CU
#define NT_TOTAL  40            // 640 output cols / 16
#define KT_TOTAL  16            // 512 K / 32
#define NWAVE     8
#define NTW       5             // n-tiles per wave
#define HSTRIDE   520           // 512 + 8 bf16 pad (stride 1040B -> 2-way LDS aliasing, free)

typedef __attribute__((ext_vector_type(8))) short bf16x8;
typedef __attribute__((ext_vector_type(4))) float f32x4;

static __device__ __forceinline__ uint16_t f2bf(float f) {
  uint32_t x = __float_as_uint(f);
  return (uint16_t)((x + 0x7fffu + ((x >> 16) & 1u)) >> 16);
}
static __device__ __forceinline__ float bf2f(uint16_t u) {
  return __uint_as_float(((uint32_t)u) << 16);
}

// E_proj[v][j] = sum_k emb[v][k]*W_ih[k][j] + b_ih[j] + b_hh[j]
__global__ void eproj_kernel(const float* __restrict__ emb,
                             const float* __restrict__ W_ih,
                             const float* __restrict__ b_ih,
                             const float* __restrict__ b_hh,
                             float* __restrict__ E) {
  __shared__ float es[HID];
  const int v = blockIdx.x;
  for (int k = threadIdx.x; k < HID; k += blockDim.x) es[k] = emb[v * HID + k];
  __syncthreads();
  for (int j = threadIdx.x; j < HID; j += blockDim.x) {
    float acc = 0.f;
#pragma unroll 4
    for (int k = 0; k < HID; ++k) acc += es[k] * W_ih[k * HID + j];
    E[v * HID + j] = acc + b_ih[j] + b_hh[j];
  }
}

// Pack [W_hh | W_ho] (512 x 640) into bf16 MFMA B-fragments.
// Fragment f = nt*16+kt is 1024B: lane l holds 8 bf16 = B[k = kt*32 + (l>>4)*8 + i][n = nt*16 + (l&15)]
__global__ void pack_kernel(const float* __restrict__ W_hh,
                            const float* __restrict__ W_ho,
                            uint32_t* __restrict__ Wf) {
  const int f = blockIdx.x;            // 0..639
  const int nt = f >> 4, kt = f & 15;
  const int lane = threadIdx.x;        // 0..63
  const int q = lane >> 4, nn = lane & 15;
  const int n = nt * 16 + nn;
  const int k0 = kt * 32 + q * 8;
  uint32_t w[4];
#pragma unroll
  for (int p = 0; p < 4; ++p) {
    const int k = k0 + 2 * p;
    float f0, f1;
    if (n < HID) { f0 = W_hh[(size_t)k * HID + n];        f1 = W_hh[(size_t)(k + 1) * HID + n]; }
    else         { f0 = W_ho[(size_t)k * VOCAB + (n - HID)]; f1 = W_ho[(size_t)(k + 1) * VOCAB + (n - HID)]; }
    w[p] = (uint32_t)f2bf(f0) | ((uint32_t)f2bf(f1) << 16);
  }
  uint4 val; val.x = w[0]; val.y = w[1]; val.z = w[2]; val.w = w[3];
  ((uint4*)Wf)[(size_t)f * 64 + lane] = val;
}

// Persistent per-batch-tile RNN. 16 blocks x 512 threads (8 waves).
// Iteration t: z = h_{t-1} @ [W_hh|W_ho]; cols<512 -> h_t = tanh(z+e_t); cols>=512 -> y_{t-1}.
__global__ __launch_bounds__(512, 2)
void rnn_kernel(const int* __restrict__ x,
                const float* __restrict__ E,
                const uint4* __restrict__ Wf,
                const float* __restrict__ b_o,
                float* __restrict__ out) {
  __shared__ uint16_t hsh[2][BT][HSTRIDE];   // bf16 h, double-buffered
  const int tid = threadIdx.x;
  const int wave = tid >> 6, lane = tid & 63;
  const int q = lane >> 4, nn = lane & 15;
  const int r0 = blockIdx.x * BT;

  // zero h buffers
  {
    uint32_t* z = (uint32_t*)hsh;
    for (int i = tid; i < 2 * BT * HSTRIDE / 2; i += 512) z[i] = 0u;
  }

  float* outY = out;                               // [B][S][V]
  float* outH = out + (size_t)BATCH * SEQ * VOCAB; // [B][H]

  // per-wave b_o prefetch for y-tiles
  float bo[NTW];
#pragma unroll
  for (int ntl = 0; ntl < NTW; ++ntl) {
    const int nt = wave * NTW + ntl;
    bo[ntl] = (nt >= 32) ? b_o[nt * 16 - HID + nn] : 0.f;
  }

  const uint4* wb = Wf + (size_t)(wave * NTW * KT_TOTAL) * 64 + lane;

  __syncthreads();

  for (int t = 0; t <= SEQ; ++t) {
    const int rb = t & 1, wbuf = rb ^ 1;

    // token + E prefetch for this step's h epilogue
    int tok[4];
    float ev[NTW][4];
    if (t < SEQ) {
#pragma unroll
      for (int r = 0; r < 4; ++r) tok[r] = x[(size_t)(r0 + q * 4 + r) * SEQ + t];
    }

    // A fragments from LDS: lane holds A[m=nn][k = kt*32 + q*8 + i]
    bf16x8 afr[KT_TOTAL];
#pragma unroll
    for (int kt = 0; kt < KT_TOTAL; ++kt) {
      const uint4 u = *(const uint4*)&hsh[rb][nn][kt * 32 + q * 8];
      afr[kt] = __builtin_bit_cast(bf16x8, u);
    }

    if (t < SEQ) {
#pragma unroll
      for (int ntl = 0; ntl < NTW; ++ntl) {
        const int nt = wave * NTW + ntl;
        if (nt < 32) {
          const int j = nt * 16 + nn;
#pragma unroll
          for (int r = 0; r < 4; ++r) ev[ntl][r] = E[(size_t)tok[r] * HID + j];
        }
      }
    }

    f32x4 acc[NTW];
#pragma unroll
    for (int i = 0; i < NTW; ++i) acc[i] = f32x4{0.f, 0.f, 0.f, 0.f};

    // B stream: 10 half-strips of 8 fragments, double-buffered (16 loads in flight)
    uint4 bA[8], bB[8];
#define LOADH(BUF, HS) { _Pragma("unroll") for (int i = 0; i < 8; ++i) BUF[i] = wb[((HS) * 8 + i) * 64]; }
#define MFMAH(BUF, HS) { _Pragma("unroll") for (int i = 0; i < 8; ++i) \
    acc[(HS) >> 1] = __builtin_amdgcn_mfma_f32_16x16x32_bf16( \
        afr[((HS) & 1) * 8 + i], __builtin_bit_cast(bf16x8, BUF[i]), acc[(HS) >> 1], 0, 0, 0); }
    LOADH(bA, 0)
    LOADH(bB, 1) MFMAH(bA, 0)
    LOADH(bA, 2) MFMAH(bB, 1)
    LOADH(bB, 3) MFMAH(bA, 2)
    LOADH(bA, 4) MFMAH(bB, 3)
    LOADH(bB, 5) MFMAH(bA, 4)
    LOADH(bA, 6) MFMAH(bB, 5)
    LOADH(bB, 7) MFMAH(bA, 6)
    LOADH(bA, 8) MFMAH(bB, 7)
    LOADH(bB, 9) MFMAH(bA, 8)
                 MFMAH(bB, 9)
#undef LOADH
#undef MFMAH

    // epilogue. D layout: row m = q*4 + r, col n = nn (measured m89/m91)
#pragma unroll
    for (int ntl = 0; ntl < NTW; ++ntl) {
      const int nt = wave * NTW + ntl;
      if (nt < 32) {
        if (t < SEQ) {
          const int j = nt * 16 + nn;
#pragma unroll
          for (int r = 0; r < 4; ++r) {
            const int m = q * 4 + r;
            const float hv = tanhf(acc[ntl][r] + ev[ntl][r]);
            hsh[wbuf][m][j] = f2bf(hv);
          }
        }
      } else {
        if (t > 0) {
          const int c = nt * 16 - HID + nn;
#pragma unroll
          for (int r = 0; r < 4; ++r) {
            const int m = q * 4 + r;
            outY[((size_t)(r0 + m) * SEQ + (t - 1)) * VOCAB + c] = acc[ntl][r] + bo[ntl];
          }
        }
      }
    }
    __syncthreads();
  }

  // hT = h_{511}, sits in buffer 0
  for (int i = tid; i < BT * HID; i += 512) {
    const int m = i >> 9, j = i & (HID - 1);
    outH[(size_t)(r0 + m) * HID + j] = bf2f(hsh[0][m][j]);
  }
}

extern "C" void kernel_launch(void* const* d_in, const int* in_sizes, int n_in,
                              void* d_out, int out_size, void* d_ws, size_t ws_size,
                              hipStream_t stream) {
  const int*   x    = (const int*)d_in[0];
  const float* emb  = (const float*)d_in[1];
  const float* W_ih = (const float*)d_in[2];
  const float* b_ih = (const float*)d_in[3];
  const float* W_hh = (const float*)d_in[4];
  const float* b_hh = (const float*)d_in[5];
  const float* W_ho = (const float*)d_in[6];
  const float* b_o  = (const float*)d_in[7];
  float* out = (float*)d_out;

  float*    E  = (float*)d_ws;                          // 128*512*4 = 262144 B
  uint32_t* Wf = (uint32_t*)((char*)d_ws + 262144);     // 40*16*1024 = 655360 B

  eproj_kernel<<<VOCAB, 256, 0, stream>>>(emb, W_ih, b_ih, b_hh, E);
  pack_kernel<<<NT_TOTAL * KT_TOTAL, 64, 0, stream>>>(W_hh, W_ho, Wf);
  rnn_kernel<<<NBLK, 512, 0, stream>>>(x, E, (const uint4*)Wf, b_o, out);
}

// Round 2
// 6643.898 us; speedup vs baseline: 1.2220x; 1.2220x over previous
//
#include <hip/hip_runtime.h>
#include <cstdint>
#include <cstddef>

#define BATCH 256
#define SEQ   512
#define HID   512
#define VOCAB 128

#define BT    16               // batch rows per block
#define HALF  256              // h-cols per block (2-way N-split)
#define LSTR  264              // LDS row stride in ushort (256 + 8 pad)

typedef __attribute__((ext_vector_type(8))) short bf16x8;
typedef __attribute__((ext_vector_type(4))) float f32x4;

static __device__ __forceinline__ uint16_t f2bf(float f) {
  uint32_t x = __float_as_uint(f);
  return (uint16_t)((x + 0x7fffu + ((x >> 16) & 1u)) >> 16);
}
static __device__ __forceinline__ float bf2f(uint16_t u) {
  return __uint_as_float(((uint32_t)u) << 16);
}
// tanh(z) = 1 - 2/(e^{2z}+1); v_exp-based, ~6 VALU ops vs ~30 for libm tanhf
static __device__ __forceinline__ float fast_tanh(float z) {
  float e = __expf(2.f * z);
  return 1.f - 2.f * __builtin_amdgcn_rcpf(e + 1.f);
}

// E[v][j] = sum_k emb[v][k]*W_ih[k][j] + b_ih[j] + b_hh[j].  16 blocks x 8 vocab rows:
// W_ih streamed once per block (16 MB total vs 128 MB in the per-v version).
__global__ __launch_bounds__(512) void eproj_kernel(const float* __restrict__ emb,
                                                    const float* __restrict__ W_ih,
                                                    const float* __restrict__ b_ih,
                                                    const float* __restrict__ b_hh,
                                                    float* __restrict__ E) {
  __shared__ float es[8][64];
  const int j = threadIdx.x;          // one thread per output col
  const int v0 = blockIdx.x * 8;
  float acc[8];
#pragma unroll
  for (int v = 0; v < 8; ++v) acc[v] = 0.f;
  for (int k0 = 0; k0 < HID; k0 += 64) {
    __syncthreads();
    es[j >> 6][j & 63] = emb[(size_t)(v0 + (j >> 6)) * HID + k0 + (j & 63)];
    __syncthreads();
#pragma unroll 8
    for (int kk = 0; kk < 64; ++kk) {
      const float w = W_ih[(size_t)(k0 + kk) * HID + j];
#pragma unroll
      for (int v = 0; v < 8; ++v) acc[v] += es[v][kk] * w;
    }
  }
  const float bias = b_ih[j] + b_hh[j];
#pragma unroll
  for (int v = 0; v < 8; ++v) E[(size_t)(v0 + v) * HID + j] = acc[v] + bias;
}

// Pack [W_hh | W_ho] (512 x 640) into bf16 MFMA B-fragments (verified layout, round 1).
// Fragment f = nt*16+kt: lane l holds 8 bf16 = B[k = kt*32 + (l>>4)*8 + i][n = nt*16 + (l&15)]
__global__ void pack_kernel(const float* __restrict__ W_hh,
                            const float* __restrict__ W_ho,
                            uint32_t* __restrict__ Wf,
                            uint32_t* __restrict__ flags) {
  const int f = blockIdx.x;            // 0..639
  if (f == 0 && threadIdx.x < 32) flags[threadIdx.x] = 0u;   // re-init every launch (ws poisoned)
  const int nt = f >> 4, kt = f & 15;
  const int lane = threadIdx.x;
  const int q = lane >> 4, nn = lane & 15;
  const int n = nt * 16 + nn;
  const int k0 = kt * 32 + q * 8;
  uint32_t w[4];
#pragma unroll
  for (int p = 0; p < 4; ++p) {
    const int k = k0 + 2 * p;
    float f0, f1;
    if (n < HID) { f0 = W_hh[(size_t)k * HID + n];           f1 = W_hh[(size_t)(k + 1) * HID + n]; }
    else         { f0 = W_ho[(size_t)k * VOCAB + (n - HID)]; f1 = W_ho[(size_t)(k + 1) * VOCAB + (n - HID)]; }
    w[p] = (uint32_t)f2bf(f0) | ((uint32_t)f2bf(f1) << 16);
  }
  uint4 val; val.x = w[0]; val.y = w[1]; val.z = w[2]; val.w = w[3];
  ((uint4*)Wf)[(size_t)f * 64 + lane] = val;
}

// Recurrence only: h_t = tanh(E[x_t] + h_{t-1} @ W_hh).
// 32 blocks = 16 batch groups x 2 column halves. Weights fully register-resident
// (128 VGPRs/wave). Pairwise exchange through Hall + monotone flags.
__global__ __launch_bounds__(512, 2)
void rnn_kernel(const int* __restrict__ x,
                const float* __restrict__ E,
                const uint4* __restrict__ Wf,
                uint16_t* __restrict__ Hall,
                uint32_t* __restrict__ flags) {
  __shared__ uint16_t hsh[BT][LSTR];    // own 256-col half of h_{t-1}, A-layout
  const int tid = threadIdx.x;
  const int wave = tid >> 6, lane = tid & 63;
  const int q = lane >> 4, nn = lane & 15;
  const int g = blockIdx.x & 15;        // batch group
  const int p = blockIdx.x >> 4;        // column half
  const int partner = blockIdx.x ^ 16;
  const int r0 = g * BT;
  const int n_base = p * HALF;          // this block's output-col base
  const int pk = (1 - p) * HALF;        // partner's col range = our missing K range

  // Preload weights. wreg[j][kk]: j = local n-tile (2 per wave), kk reordered so
  // kk<8 = OWN k-range (LDS phase), kk>=8 = partner k-range -> all indices compile-time.
  bf16x8 wreg[2][16];
  {
    const uint4* wb = Wf + lane;
#pragma unroll
    for (int j = 0; j < 2; ++j) {
      const int ntg = p * 16 + 2 * wave + j;
#pragma unroll
      for (int kk = 0; kk < 16; ++kk) {
        const int ktg = (kk + 8 * p) & 15;
        wreg[j][kk] = __builtin_bit_cast(bf16x8, wb[(size_t)(ntg * 16 + ktg) * 64]);
      }
    }
  }

  for (int t = 0; t < SEQ; ++t) {
    // prefetch E rows for this step's epilogue
    float ev[2][4];
#pragma unroll
    for (int r = 0; r < 4; ++r) {
      const int tok = x[(size_t)(r0 + q * 4 + r) * SEQ + t];
#pragma unroll
      for (int j = 0; j < 2; ++j)
        ev[j][r] = E[(size_t)tok * HID + n_base + (2 * wave + j) * 16 + nn];
    }

    f32x4 acc0 = {0.f, 0.f, 0.f, 0.f}, acc1 = {0.f, 0.f, 0.f, 0.f};

    if (t > 0) {
      // phase 1: own half from LDS (no partner dependency -> issues before the spin)
#pragma unroll
      for (int kk = 0; kk < 8; ++kk) {
        const uint4 u = *(const uint4*)&hsh[nn][kk * 32 + q * 8];
        const bf16x8 a = __builtin_bit_cast(bf16x8, u);
        acc0 = __builtin_amdgcn_mfma_f32_16x16x32_bf16(a, wreg[0][kk], acc0, 0, 0, 0);
        acc1 = __builtin_amdgcn_mfma_f32_16x16x32_bf16(a, wreg[1][kk], acc1, 0, 0, 0);
      }
      // wait for partner's h_{t-1} half (all lanes poll same dword; per-thread acquire)
      while (__hip_atomic_load(&flags[partner], __ATOMIC_ACQUIRE,
                               __HIP_MEMORY_SCOPE_AGENT) < (uint32_t)t) {}
      // phase 2: partner half straight from Hall (L2-hit; 8 waves reuse via L1)
      const uint16_t* hp = Hall + ((size_t)(r0 + nn) * SEQ + (t - 1)) * HID + pk + q * 8;
#pragma unroll
      for (int kk = 8; kk < 16; ++kk) {
        const uint4 u = *(const uint4*)(hp + (kk - 8) * 32);
        const bf16x8 a = __builtin_bit_cast(bf16x8, u);
        acc0 = __builtin_amdgcn_mfma_f32_16x16x32_bf16(a, wreg[0][kk], acc0, 0, 0, 0);
        acc1 = __builtin_amdgcn_mfma_f32_16x16x32_bf16(a, wreg[1][kk], acc1, 0, 0, 0);
      }
    }

    __syncthreads();   // all phase-1 LDS reads done before hsh is overwritten

    // epilogue: h = tanh(z + ev); D layout row m=q*4+r, col nn (verified r1)
#pragma unroll
    for (int j = 0; j < 2; ++j) {
      const int lc = (2 * wave + j) * 16 + nn;     // local col 0..255
#pragma unroll
      for (int r = 0; r < 4; ++r) {
        const int m = q * 4 + r;
        const float z = (j == 0 ? acc0[r] : acc1[r]) + ev[j][r];
        const uint16_t hb = f2bf(fast_tanh(z));
        hsh[m][lc] = hb;
        Hall[((size_t)(r0 + m) * SEQ + t) * HID + n_base + lc] = hb;
      }
    }
    __threadfence();       // make Hall writes agent-visible
    __syncthreads();       // order all threads' fences before the flag release
    if (tid == 0)
      __hip_atomic_store(&flags[blockIdx.x], (uint32_t)(t + 1),
                         __ATOMIC_RELEASE, __HIP_MEMORY_SCOPE_AGENT);
  }
}

// Y[b,s,:] = h_{b,s} @ W_ho + b_o over all 131072 rows — fully parallel.
__global__ __launch_bounds__(256)
void ygemm_kernel(const uint16_t* __restrict__ Hall,
                  const uint4* __restrict__ Wf,
                  const float* __restrict__ b_o,
                  float* __restrict__ out) {
  const int tid = threadIdx.x;
  const int wave = tid >> 6, lane = tid & 63;
  const int q = lane >> 4, nn = lane & 15;
  const size_t row0 = (size_t)blockIdx.x * 64 + (size_t)wave * 16;
  f32x4 acc[8];
#pragma unroll
  for (int i = 0; i < 8; ++i) acc[i] = f32x4{0.f, 0.f, 0.f, 0.f};
  const uint16_t* ha = Hall + (row0 + nn) * HID + q * 8;
  const uint4* wb = Wf + (size_t)(32 * 16) * 64 + lane;   // W_ho fragments: nt 32..39
#pragma unroll 4
  for (int kt = 0; kt < 16; ++kt) {
    const bf16x8 a = __builtin_bit_cast(bf16x8, *(const uint4*)(ha + kt * 32));
#pragma unroll
    for (int nt = 0; nt < 8; ++nt) {
      const bf16x8 b = __builtin_bit_cast(bf16x8, wb[(size_t)(nt * 16 + kt) * 64]);
      acc[nt] = __builtin_amdgcn_mfma_f32_16x16x32_bf16(a, b, acc[nt], 0, 0, 0);
    }
  }
#pragma unroll
  for (int nt = 0; nt < 8; ++nt) {
    const float bo = b_o[nt * 16 + nn];
#pragma unroll
    for (int r = 0; r < 4; ++r)
      out[(row0 + q * 4 + r) * VOCAB + nt * 16 + nn] = acc[nt][r] + bo;
  }
}

__global__ __launch_bounds__(512)
void ht_kernel(const uint16_t* __restrict__ Hall, float* __restrict__ outH) {
  const int i = blockIdx.x * 512 + threadIdx.x;   // 0..131071
  const int b = i >> 9, h = i & (HID - 1);
  outH[i] = bf2f(Hall[((size_t)b * SEQ + (SEQ - 1)) * HID + h]);
}

extern "C" void kernel_launch(void* const* d_in, const int* in_sizes, int n_in,
                              void* d_out, int out_size, void* d_ws, size_t ws_size,
                              hipStream_t stream) {
  const int*   x    = (const int*)d_in[0];
  const float* emb  = (const float*)d_in[1];
  const float* W_ih = (const float*)d_in[2];
  const float* b_ih = (const float*)d_in[3];
  const float* W_hh = (const float*)d_in[4];
  const float* b_hh = (const float*)d_in[5];
  const float* W_ho = (const float*)d_in[6];
  const float* b_o  = (const float*)d_in[7];
  float* out = (float*)d_out;

  char* ws = (char*)d_ws;
  float*    E     = (float*)ws;                              // 256 KB
  uint32_t* Wf    = (uint32_t*)(ws + (256 << 10));           // 640 KB
  uint32_t* flags = (uint32_t*)(ws + (896 << 10));           // 128 B
  uint16_t* Hall  = (uint16_t*)(ws + (1 << 20));             // 128 MB: h_t for all (b,s)

  eproj_kernel<<<VOCAB / 8, 512, 0, stream>>>(emb, W_ih, b_ih, b_hh, E);
  pack_kernel<<<640, 64, 0, stream>>>(W_hh, W_ho, Wf, flags);
  rnn_kernel<<<32, 512, 0, stream>>>(x, E, (const uint4*)Wf, Hall, flags);
  ygemm_kernel<<<(BATCH * SEQ) / 64, 256, 0, stream>>>(Hall, (const uint4*)Wf, b_o, out);
  ht_kernel<<<BATCH * HID / 512, 512, 0, stream>>>(Hall, out + (size_t)BATCH * SEQ * VOCAB);
}

// Round 3
// 1310.491 us; speedup vs baseline: 6.1952x; 5.0698x over previous
//
#include <hip/hip_runtime.h>
#include <cstdint>
#include <cstddef>

#define BATCH 256
#define SEQ   512
#define HID   512
#define VOCAB 128

#define BT    16               // batch rows per block
#define HSTR  520              // h-buffer row stride in shorts (1040 B)
#define LWF_BYTES  131072      // 8 strips * 16 frags * 1024 B
#define HBUF_BYTES (BT * HSTR * 2)
#define SMEM_BYTES (LWF_BYTES + HBUF_BYTES)   // 147712

typedef __attribute__((ext_vector_type(8))) short bf16x8;
typedef __attribute__((ext_vector_type(4))) float f32x4;

static __device__ __forceinline__ uint16_t f2bf(float f) {
  uint32_t x = __float_as_uint(f);
  return (uint16_t)((x + 0x7fffu + ((x >> 16) & 1u)) >> 16);
}
static __device__ __forceinline__ float bf2f(uint16_t u) {
  return __uint_as_float(((uint32_t)u) << 16);
}
// tanh(z) = 1 - 2/(e^{2z}+1); saturates correctly at +/-inf
static __device__ __forceinline__ float fast_tanh(float z) {
  float e = __expf(2.f * z);
  return 1.f - 2.f * __builtin_amdgcn_rcpf(e + 1.f);
}

// E[v][j] = sum_k emb[v][k]*W_ih[k][j] + b_ih[j] + b_hh[j]
__global__ __launch_bounds__(512) void eproj_kernel(const float* __restrict__ emb,
                                                    const float* __restrict__ W_ih,
                                                    const float* __restrict__ b_ih,
                                                    const float* __restrict__ b_hh,
                                                    float* __restrict__ E) {
  __shared__ float es[8][64];
  const int j = threadIdx.x;
  const int v0 = blockIdx.x * 8;
  float acc[8];
#pragma unroll
  for (int v = 0; v < 8; ++v) acc[v] = 0.f;
  for (int k0 = 0; k0 < HID; k0 += 64) {
    __syncthreads();
    es[j >> 6][j & 63] = emb[(size_t)(v0 + (j >> 6)) * HID + k0 + (j & 63)];
    __syncthreads();
#pragma unroll 8
    for (int kk = 0; kk < 64; ++kk) {
      const float w = W_ih[(size_t)(k0 + kk) * HID + j];
#pragma unroll
      for (int v = 0; v < 8; ++v) acc[v] += es[v][kk] * w;
    }
  }
  const float bias = b_ih[j] + b_hh[j];
#pragma unroll
  for (int v = 0; v < 8; ++v) E[(size_t)(v0 + v) * HID + j] = acc[v] + bias;
}

// Pack [W_hh | W_ho] (512 x 640) into bf16 MFMA B-fragments (layout verified r1/r2).
// Fragment f = nt*16+kt: lane l holds 8 bf16 = B[k = kt*32 + (l>>4)*8 + i][n = nt*16 + (l&15)]
__global__ void pack_kernel(const float* __restrict__ W_hh,
                            const float* __restrict__ W_ho,
                            uint32_t* __restrict__ Wf) {
  const int f = blockIdx.x;            // 0..639
  const int nt = f >> 4, kt = f & 15;
  const int lane = threadIdx.x;
  const int q = lane >> 4, nn = lane & 15;
  const int n = nt * 16 + nn;
  const int k0 = kt * 32 + q * 8;
  uint32_t w[4];
#pragma unroll
  for (int p = 0; p < 4; ++p) {
    const int k = k0 + 2 * p;
    float f0, f1;
    if (n < HID) { f0 = W_hh[(size_t)k * HID + n];           f1 = W_hh[(size_t)(k + 1) * HID + n]; }
    else         { f0 = W_ho[(size_t)k * VOCAB + (n - HID)]; f1 = W_ho[(size_t)(k + 1) * VOCAB + (n - HID)]; }
    w[p] = (uint32_t)f2bf(f0) | ((uint32_t)f2bf(f1) << 16);
  }
  uint4 val; val.x = w[0]; val.y = w[1]; val.z = w[2]; val.w = w[3];
  ((uint4*)Wf)[(size_t)f * 64 + lane] = val;
}

// Recurrence: h_t = tanh(E[x_t] + h_{t-1} @ W_hh), y deferred to ygemm.
// 16 blocks x 512 threads (8 waves). Wave w owns n-tiles w*4..w*4+3:
// 3 strips register-resident (pinned), strip 3 in LDS. NO inter-block sync.
__global__ __launch_bounds__(512)
void rnn_kernel(const int* __restrict__ x,
                const float* __restrict__ E,
                const uint4* __restrict__ Wf,
                uint16_t* __restrict__ Hall) {
  extern __shared__ char smem[];
  uint4*    lwf  = (uint4*)smem;                    // 8192 uint4 = 128 KB
  uint16_t* hbuf = (uint16_t*)(smem + LWF_BYTES);   // [BT][HSTR]

  const int tid = threadIdx.x;
  const int wave = tid >> 6, lane = tid & 63;
  const int q = lane >> 4, nn = lane & 15;
  const int r0 = blockIdx.x * BT;

  // stage the 8 LDS strips (nt = w*4+3 for wave w)
  for (int i = tid; i < 8192; i += 512) {
    const int w = i >> 10, kt = (i >> 6) & 15, ln = i & 63;
    lwf[i] = Wf[(size_t)(((w * 4 + 3) * 16 + kt)) * 64 + ln];
  }

  // register strips, pinned so the compiler cannot sink the loads into the loop
  bf16x8 wreg[3][16];
  {
    const uint4* wb = Wf + lane;
#pragma unroll
    for (int j = 0; j < 3; ++j)
#pragma unroll
      for (int kt = 0; kt < 16; ++kt)
        wreg[j][kt] = __builtin_bit_cast(bf16x8, wb[(size_t)((wave * 4 + j) * 16 + kt) * 64]);
  }
#pragma unroll
  for (int j = 0; j < 3; ++j)
#pragma unroll
    for (int kt = 0; kt < 16; ++kt)
      asm volatile("" : "+v"(wreg[j][kt]));

  const uint4* lws = lwf + (size_t)wave * 16 * 64 + lane;   // this wave's LDS strip

  __syncthreads();

  // token prefetch for t=0
  int tokc[4];
#pragma unroll
  for (int r = 0; r < 4; ++r) tokc[r] = x[(size_t)(r0 + q * 4 + r) * SEQ + 0];

  for (int t = 0; t < SEQ; ++t) {
    // prefetch next step's tokens (independent of everything below)
    int tokn[4];
    const int tn = (t + 1 < SEQ) ? t + 1 : t;
#pragma unroll
    for (int r = 0; r < 4; ++r) tokn[r] = x[(size_t)(r0 + q * 4 + r) * SEQ + tn];

    // acc initialized from E (C-operand of the first MFMA) — includes both biases
    f32x4 acc[4];
#pragma unroll
    for (int j = 0; j < 4; ++j)
#pragma unroll
      for (int r = 0; r < 4; ++r)
        acc[j][r] = E[(size_t)tokc[r] * HID + wave * 64 + j * 16 + nn];

    if (t > 0) {
#pragma unroll
      for (int kt = 0; kt < 16; ++kt) {
        const bf16x8 a  = __builtin_bit_cast(bf16x8,
            *(const uint4*)&hbuf[nn * HSTR + kt * 32 + q * 8]);
        const bf16x8 wl = __builtin_bit_cast(bf16x8, lws[kt * 64]);
        acc[0] = __builtin_amdgcn_mfma_f32_16x16x32_bf16(a, wreg[0][kt], acc[0], 0, 0, 0);
        acc[1] = __builtin_amdgcn_mfma_f32_16x16x32_bf16(a, wreg[1][kt], acc[1], 0, 0, 0);
        acc[2] = __builtin_amdgcn_mfma_f32_16x16x32_bf16(a, wreg[2][kt], acc[2], 0, 0, 0);
        acc[3] = __builtin_amdgcn_mfma_f32_16x16x32_bf16(a, wl,          acc[3], 0, 0, 0);
      }
    }
    __syncthreads();   // hbuf reads done before overwrite

    // epilogue: h = tanh(z); D layout row m=q*4+r, col nn (verified)
#pragma unroll
    for (int j = 0; j < 4; ++j) {
      const int col = wave * 64 + j * 16 + nn;
#pragma unroll
      for (int r = 0; r < 4; ++r) {
        const int m = q * 4 + r;
        const uint16_t hb = f2bf(fast_tanh(acc[j][r]));
        hbuf[m * HSTR + col] = hb;
        Hall[((size_t)(r0 + m) * SEQ + t) * HID + col] = hb;
      }
    }
    __syncthreads();   // hbuf writes done before next step's reads

#pragma unroll
    for (int r = 0; r < 4; ++r) tokc[r] = tokn[r];
  }
}

// Y[b,s,:] = h_{b,s} @ W_ho + b_o over all 131072 rows — fully parallel.
__global__ __launch_bounds__(256)
void ygemm_kernel(const uint16_t* __restrict__ Hall,
                  const uint4* __restrict__ Wf,
                  const float* __restrict__ b_o,
                  float* __restrict__ out) {
  const int tid = threadIdx.x;
  const int wave = tid >> 6, lane = tid & 63;
  const int q = lane >> 4, nn = lane & 15;
  const size_t row0 = (size_t)blockIdx.x * 64 + (size_t)wave * 16;
  f32x4 acc[8];
#pragma unroll
  for (int i = 0; i < 8; ++i) acc[i] = f32x4{0.f, 0.f, 0.f, 0.f};
  const uint16_t* ha = Hall + (row0 + nn) * HID + q * 8;
  const uint4* wb = Wf + (size_t)(32 * 16) * 64 + lane;   // W_ho fragments: nt 32..39
#pragma unroll 4
  for (int kt = 0; kt < 16; ++kt) {
    const bf16x8 a = __builtin_bit_cast(bf16x8, *(const uint4*)(ha + kt * 32));
#pragma unroll
    for (int nt = 0; nt < 8; ++nt) {
      const bf16x8 b = __builtin_bit_cast(bf16x8, wb[(size_t)(nt * 16 + kt) * 64]);
      acc[nt] = __builtin_amdgcn_mfma_f32_16x16x32_bf16(a, b, acc[nt], 0, 0, 0);
    }
  }
#pragma unroll
  for (int nt = 0; nt < 8; ++nt) {
    const float bo = b_o[nt * 16 + nn];
#pragma unroll
    for (int r = 0; r < 4; ++r)
      out[(row0 + q * 4 + r) * VOCAB + nt * 16 + nn] = acc[nt][r] + bo;
  }
}

__global__ __launch_bounds__(512)
void ht_kernel(const uint16_t* __restrict__ Hall, float* __restrict__ outH) {
  const int i = blockIdx.x * 512 + threadIdx.x;
  const int b = i >> 9, h = i & (HID - 1);
  outH[i] = bf2f(Hall[((size_t)b * SEQ + (SEQ - 1)) * HID + h]);
}

extern "C" void kernel_launch(void* const* d_in, const int* in_sizes, int n_in,
                              void* d_out, int out_size, void* d_ws, size_t ws_size,
                              hipStream_t stream) {
  const int*   x    = (const int*)d_in[0];
  const float* emb  = (const float*)d_in[1];
  const float* W_ih = (const float*)d_in[2];
  const float* b_ih = (const float*)d_in[3];
  const float* W_hh = (const float*)d_in[4];
  const float* b_hh = (const float*)d_in[5];
  const float* W_ho = (const float*)d_in[6];
  const float* b_o  = (const float*)d_in[7];
  float* out = (float*)d_out;

  char* ws = (char*)d_ws;
  float*    E    = (float*)ws;                              // 256 KB
  uint32_t* Wf   = (uint32_t*)(ws + (256 << 10));           // 640 KB
  uint16_t* Hall = (uint16_t*)(ws + (1 << 20));             // 128 MB

  // opt-in to >64 KB dynamic LDS (idempotent; immediate-mode API, capture-safe)
  (void)hipFuncSetAttribute((const void*)rnn_kernel,
                            hipFuncAttributeMaxDynamicSharedMemorySize, SMEM_BYTES);

  eproj_kernel<<<VOCAB / 8, 512, 0, stream>>>(emb, W_ih, b_ih, b_hh, E);
  pack_kernel<<<640, 64, 0, stream>>>(W_hh, W_ho, Wf);
  rnn_kernel<<<16, 512, SMEM_BYTES, stream>>>(x, E, (const uint4*)Wf, Hall);
  ygemm_kernel<<<(BATCH * SEQ) / 64, 256, 0, stream>>>(Hall, (const uint4*)Wf, b_o, out);
  ht_kernel<<<BATCH * HID / 512, 512, 0, stream>>>(Hall, out + (size_t)BATCH * SEQ * VOCAB);
}